// Round 1
// baseline (655.606 us; speedup 1.0000x reference)
//
#include <hip/hip_runtime.h>
#include <stdint.h>

#define PN 24564
#define BN 64
#define MN 32
#define CN 81

typedef float f4 __attribute__((ext_vector_type(4)));
typedef unsigned long long u64;
typedef unsigned int u32;

// ---------------- workspace layout ----------------
constexpr size_t SZ_BP4  = (size_t)BN * PN * 4;        // 6,288,384
constexpr size_t OFF_OVL = SZ_BP4;                     // best_ovl f32
constexpr size_t OFF_IDX = 2 * SZ_BP4;                 // best_idx i32
constexpr size_t OFF_PACK = 3 * SZ_BP4;                // packed u64 [BN*MN]
constexpr size_t SZ_PACK = (size_t)BN * MN * 8;        // 16,384
constexpr size_t OFF_PCNT = OFF_PACK + SZ_PACK;        // per-batch pos count
constexpr size_t OFF_NP   = OFF_PCNT + BN * 4;         // global num_pos
constexpr size_t OFF_ACC  = OFF_NP + 8;                // 3 doubles: sl1, ce_pos, ce_neg
constexpr size_t TAIL_SZ  = SZ_PACK + BN * 4 + 8 + 24;

__device__ __forceinline__ float sl1f(float d) {
  float ad = fabsf(d);
  return ad < 1.0f ? 0.5f * d * d : ad - 0.5f;
}

__device__ __forceinline__ u64 shfl_xor_u64(u64 v, int m) {
  u32 lo = (u32)v, hi = (u32)(v >> 32);
  lo = (u32)__shfl_xor((int)lo, m, 64);
  hi = (u32)__shfl_xor((int)hi, m, 64);
  return ((u64)hi << 32) | lo;
}

// ---------------- K1: matching ----------------
__global__ void k_match(const f4* __restrict__ priors,
                        const f4* __restrict__ gt_boxes,
                        float* __restrict__ best_ovl,
                        int* __restrict__ best_idx,
                        u64* __restrict__ packed_best)
{
  const int b = blockIdx.y;
  const int tid = threadIdx.x;
  __shared__ f4 gt[MN];
  __shared__ float ga[MN];
  if (tid < MN) {
    f4 g = gt_boxes[b * MN + tid];
    gt[tid] = g;
    ga[tid] = (g.z - g.x) * (g.w - g.y);
  }
  __syncthreads();

  u64 lb[MN];
#pragma unroll
  for (int m = 0; m < MN; m++) lb[m] = 0ull;

  for (int p = blockIdx.x * blockDim.x + tid; p < PN; p += gridDim.x * blockDim.x) {
    f4 pr = priors[p];
    float px0 = pr.x - pr.z * 0.5f;
    float py0 = pr.y - pr.w * 0.5f;
    float px1 = pr.x + pr.z * 0.5f;
    float py1 = pr.y + pr.w * 0.5f;
    float pa  = (px1 - px0) * (py1 - py0);
    float bov = -1.0f; int bi = 0;
    u32 key = 0xFFFFFFFFu - (u32)p;   // larger key = smaller p -> first-occurrence ties
#pragma unroll
    for (int m = 0; m < MN; m++) {
      f4 g = gt[m];
      float iw = fminf(px1, g.z) - fmaxf(px0, g.x);
      float ih = fminf(py1, g.w) - fmaxf(py0, g.y);
      iw = fmaxf(iw, 0.0f); ih = fmaxf(ih, 0.0f);
      float inter = iw * ih;
      float iou = inter / (pa + ga[m] - inter);
      if (iou > bov) { bov = iou; bi = m; }
      u64 pk = ((u64)__float_as_uint(iou) << 32) | key;
      if (pk > lb[m]) lb[m] = pk;
    }
    best_ovl[(size_t)b * PN + p] = bov;
    best_idx[(size_t)b * PN + p] = bi;
  }

  __shared__ u64 wred[4][MN];
  const int lane = tid & 63, wv = tid >> 6;
#pragma unroll
  for (int m = 0; m < MN; m++) {
    u64 v = lb[m];
#pragma unroll
    for (int off = 1; off < 64; off <<= 1) {
      u64 o = shfl_xor_u64(v, off);
      if (o > v) v = o;
    }
    if (lane == 0) wred[wv][m] = v;
  }
  __syncthreads();
  if (tid < MN) {
    u64 v = wred[0][tid];
    for (int w = 1; w < (int)(blockDim.x >> 6); w++) {
      u64 o = wred[w][tid]; if (o > v) v = o;
    }
    atomicMax(&packed_best[b * MN + tid], v);
  }
}

// ---------------- K2: scatter override (sequential last-wins per batch) ----------------
__global__ void k_override(const u64* __restrict__ packed,
                           float* __restrict__ best_ovl,
                           int* __restrict__ best_idx)
{
  int b = threadIdx.x;
  if (b >= BN) return;
  for (int m = 0; m < MN; m++) {
    u64 pk = packed[b * MN + m];
    u32 pidx = 0xFFFFFFFFu - (u32)(pk & 0xFFFFFFFFull);
    best_idx[(size_t)b * PN + pidx] = m;
    best_ovl[(size_t)b * PN + pidx] = 1.0f;
  }
}

// ---------------- K3: fused loc loss + CE (the hot, memory-bound kernel) ----------------
__global__ void k_big(const f4* __restrict__ loc_preds,
                      const float* __restrict__ conf_preds,
                      const f4* __restrict__ priors,
                      const f4* __restrict__ gt_boxes,
                      const int* __restrict__ gt_labels,
                      const float* __restrict__ best_ovl,
                      const int* __restrict__ best_idx,
                      float* __restrict__ ce_neg,
                      int* __restrict__ pos_cnt,
                      int* __restrict__ num_pos,
                      double* __restrict__ acc)
{
  const int b = blockIdx.y;
  const int p = blockIdx.x * blockDim.x + threadIdx.x;
  float my_sl1 = 0.f, my_cep = 0.f; int my_pos = 0;
  if (p < PN) {
    const size_t rp = (size_t)b * PN + p;
    const float ovl = best_ovl[rp];
    const int gi = best_idx[rp];
    const bool pos = ovl > 0.5f;
    int cls = 0;
    if (pos) {
      cls = gt_labels[b * MN + gi];
      f4 g = gt_boxes[b * MN + gi];
      f4 pr = priors[p];
      float gx = (g.x + g.z) * 0.5f, gy = (g.y + g.w) * 0.5f;
      float gw = g.z - g.x, gh = g.w - g.y;
      f4 lp = loc_preds[rp];
      float d0 = lp.x - (gx - pr.x) / pr.z;
      float d1 = lp.y - (gy - pr.y) / pr.w;
      float d2 = lp.z - logf(gw / pr.z);
      float d3 = lp.w - logf(gh / pr.w);
      my_sl1 = sl1f(d0) + sl1f(d1) + sl1f(d2) + sl1f(d3);
      my_pos = 1;
    }
    const float* row = conf_preds + rp * (size_t)CN;
    float xt = row[cls];
    const f4* vrow = (const f4*)row;   // 4B-aligned; dwordx4 is dword-aligned-legal on CDNA
    float mx = -3.0e38f, s = 0.f;
#pragma unroll
    for (int i = 0; i < 20; i++) {
      f4 v = vrow[i];
      float m4 = fmaxf(fmaxf(v.x, v.y), fmaxf(v.z, v.w));
      float nm = fmaxf(mx, m4);
      s = s * __expf(mx - nm) + __expf(v.x - nm) + __expf(v.y - nm)
            + __expf(v.z - nm) + __expf(v.w - nm);
      mx = nm;
    }
    {
      float x = row[80];
      float nm = fmaxf(mx, x);
      s = s * __expf(mx - nm) + __expf(x - nm);
      mx = nm;
    }
    float ce = mx + logf(s) - xt;
    ce = fmaxf(ce, 0.0f);   // keep bits sign-free for radix select
    if (pos) { my_cep = ce; ce_neg[rp] = 0.0f; }
    else     { ce_neg[rp] = ce; }
  }
  // block reduce (double) -> one atomic per block
  double dsl = (double)my_sl1, dce = (double)my_cep;
  int pc = my_pos;
#pragma unroll
  for (int off = 1; off < 64; off <<= 1) {
    dsl += __shfl_xor(dsl, off, 64);
    dce += __shfl_xor(dce, off, 64);
    pc  += __shfl_xor(pc, off, 64);
  }
  __shared__ double ssl[4], sce[4]; __shared__ int spc[4];
  const int lane = threadIdx.x & 63, wv = threadIdx.x >> 6;
  if (lane == 0) { ssl[wv] = dsl; sce[wv] = dce; spc[wv] = pc; }
  __syncthreads();
  if (threadIdx.x == 0) {
    double a = ssl[0] + ssl[1] + ssl[2] + ssl[3];
    double c = sce[0] + sce[1] + sce[2] + sce[3];
    int q = spc[0] + spc[1] + spc[2] + spc[3];
    if (a != 0.0) atomicAdd(&acc[0], a);
    if (c != 0.0) atomicAdd(&acc[1], c);
    if (q) { atomicAdd(num_pos, q); atomicAdd(&pos_cnt[b], q); }
  }
}

// ---------------- K4: per-batch exact top-k sum via radix select ----------------
__global__ __launch_bounds__(1024)
void k_topk(const float* __restrict__ ce_neg,
            const int* __restrict__ pos_cnt,
            double* __restrict__ acc)
{
  const int b = blockIdx.x;
  const float* row = ce_neg + (size_t)b * PN;
  int k = pos_cnt[b] * 3;
  if (k < 1) k = 1;
  if (k > PN) k = PN;

  const int tid = threadIdx.x;
  const int wv = tid >> 6;
  __shared__ u32 hist[16][256];
  __shared__ u32 sh_prefix; __shared__ int sh_rem;

  u32 prefix = 0; int rem = k;
  for (int shift = 24; shift >= 0; shift -= 8) {
    for (int i = tid; i < 16 * 256; i += blockDim.x) ((u32*)hist)[i] = 0;
    __syncthreads();
    const u32 pmask = (shift == 24) ? 0u : (0xFFFFFFFFu << (shift + 8));
    for (int p = tid; p < PN; p += blockDim.x) {
      u32 u = __float_as_uint(row[p]);
      if ((u & pmask) == (prefix & pmask))
        atomicAdd(&hist[wv][(u >> shift) & 255], 1u);
    }
    __syncthreads();
    if (tid < 256) {
      u32 c = 0;
#pragma unroll
      for (int w = 0; w < 16; w++) c += hist[w][tid];
      hist[0][tid] = c;
    }
    __syncthreads();
    if (tid == 0) {
      u32 c = 0; int d = 255;
      for (; d >= 0; d--) { c += hist[0][d]; if ((int)c >= rem) break; }
      if (d < 0) d = 0;
      sh_prefix = prefix | ((u32)d << shift);
      sh_rem = rem - (int)(c - hist[0][d]);
    }
    __syncthreads();
    prefix = sh_prefix; rem = sh_rem;
    __syncthreads();
  }

  const float vstar = __uint_as_float(prefix);
  double sg = 0.0;
  for (int p = tid; p < PN; p += blockDim.x) {
    float v = row[p];
    if (__float_as_uint(v) > prefix) sg += (double)v;
  }
#pragma unroll
  for (int off = 1; off < 64; off <<= 1) sg += __shfl_xor(sg, off, 64);
  __shared__ double sred[16];
  if ((tid & 63) == 0) sred[wv] = sg;
  __syncthreads();
  if (tid == 0) {
    double t = 0;
    for (int w = 0; w < 16; w++) t += sred[w];
    t += (double)rem * (double)vstar;   // ties at v* contribute identically to any stable order
    atomicAdd(&acc[2], t);
  }
}

// ---------------- K5: finalize ----------------
__global__ void k_final(const double* __restrict__ acc,
                        const int* __restrict__ num_pos,
                        float* __restrict__ out)
{
  int np = *num_pos; if (np < 1) np = 1;
  out[0] = (float)((acc[0] + acc[1] + acc[2]) / (double)np);
}

extern "C" void kernel_launch(void* const* d_in, const int* in_sizes, int n_in,
                              void* d_out, int out_size, void* d_ws, size_t ws_size,
                              hipStream_t stream)
{
  const f4*    loc    = (const f4*)d_in[0];
  const float* conf   = (const float*)d_in[1];
  const f4*    priors = (const f4*)d_in[2];
  const f4*    gt     = (const f4*)d_in[3];
  const int*   labels = (const int*)d_in[4];

  char* ws = (char*)d_ws;
  float* ce_neg   = (float*)(ws);
  float* best_ovl = (float*)(ws + OFF_OVL);
  int*   best_idx = (int*)(ws + OFF_IDX);
  u64*   packed   = (u64*)(ws + OFF_PACK);
  int*   pos_cnt  = (int*)(ws + OFF_PCNT);
  int*   num_pos  = (int*)(ws + OFF_NP);
  double* acc     = (double*)(ws + OFF_ACC);

  hipMemsetAsync(ws + OFF_PACK, 0, TAIL_SZ, stream);

  k_match<<<dim3(12, BN), 256, 0, stream>>>(priors, gt, best_ovl, best_idx, packed);
  k_override<<<1, 64, 0, stream>>>(packed, best_ovl, best_idx);
  k_big<<<dim3((PN + 255) / 256, BN), 256, 0, stream>>>(loc, conf, priors, gt, labels,
                                                        best_ovl, best_idx, ce_neg,
                                                        pos_cnt, num_pos, acc);
  k_topk<<<BN, 1024, 0, stream>>>(ce_neg, pos_cnt, acc);
  k_final<<<1, 1, 0, stream>>>(acc, num_pos, (float*)d_out);
}

// Round 2
// 432.839 us; speedup vs baseline: 1.5147x; 1.5147x over previous
//
#include <hip/hip_runtime.h>
#include <stdint.h>

#define PN 24564
#define BN 64
#define MN 32
#define CN 81
#define MG 4   // gt boxes per block in k_gt_best

typedef float f4 __attribute__((ext_vector_type(4)));
typedef unsigned long long u64;
typedef unsigned int u32;

// ---------------- workspace layout ----------------
constexpr size_t SZ_BP4   = (size_t)BN * PN * 4;        // 6,288,384
constexpr size_t OFF_OVL  = SZ_BP4;                     // best_ovl f32
constexpr size_t OFF_IDX  = 2 * SZ_BP4;                 // best_idx i32
constexpr size_t OFF_PACK = 3 * SZ_BP4;                 // packed u64 [BN*MN]
constexpr size_t SZ_PACK  = (size_t)BN * MN * 8;        // 16,384
constexpr size_t OFF_PCNT = OFF_PACK + SZ_PACK;         // per-batch pos count (BN i32)
constexpr size_t OFF_NP   = OFF_PCNT + BN * 4;          // global num_pos
constexpr size_t OFF_ACC  = OFF_NP + 8;                 // 3 doubles
constexpr size_t ZERO_OFF = OFF_PCNT;
constexpr size_t ZERO_SZ  = BN * 4 + 8 + 24;

__device__ __forceinline__ float sl1f(float d) {
  float ad = fabsf(d);
  return ad < 1.0f ? 0.5f * d * d : ad - 0.5f;
}

__device__ __forceinline__ u64 shfl_xor_u64(u64 v, int m) {
  u32 lo = (u32)v, hi = (u32)(v >> 32);
  lo = (u32)__shfl_xor((int)lo, m, 64);
  hi = (u32)__shfl_xor((int)hi, m, 64);
  return ((u64)hi << 32) | lo;
}

// ---------------- K1a: per-prior best gt (max/argmax over m) ----------------
__global__ __launch_bounds__(256)
void k_prior_best(const f4* __restrict__ priors,
                  const f4* __restrict__ gt_boxes,
                  float* __restrict__ best_ovl,
                  int* __restrict__ best_idx)
{
  const int b = blockIdx.y;
  const int tid = threadIdx.x;
  __shared__ f4 gt[MN];
  __shared__ float ga[MN];
  if (tid < MN) {
    f4 g = gt_boxes[b * MN + tid];
    gt[tid] = g;
    ga[tid] = (g.z - g.x) * (g.w - g.y);
  }
  __syncthreads();
  const int p = blockIdx.x * 256 + tid;
  if (p >= PN) return;
  f4 pr = priors[p];
  float px0 = pr.x - pr.z * 0.5f;
  float py0 = pr.y - pr.w * 0.5f;
  float px1 = pr.x + pr.z * 0.5f;
  float py1 = pr.y + pr.w * 0.5f;
  float pa  = (px1 - px0) * (py1 - py0);
  float bov = -1.0f; int bi = 0;
#pragma unroll
  for (int m = 0; m < MN; m++) {
    f4 g = gt[m];
    float iw = fmaxf(fminf(px1, g.z) - fmaxf(px0, g.x), 0.0f);
    float ih = fmaxf(fminf(py1, g.w) - fmaxf(py0, g.y), 0.0f);
    float inter = iw * ih;
    float iou = inter / (pa + ga[m] - inter);
    if (iou > bov) { bov = iou; bi = m; }
  }
  best_ovl[(size_t)b * PN + p] = bov;
  best_idx[(size_t)b * PN + p] = bi;
}

// ---------------- K1b: per-gt best prior (argmax over p), 4 gt per block ----
__global__ __launch_bounds__(256)
void k_gt_best(const f4* __restrict__ priors,
               const f4* __restrict__ gt_boxes,
               u64* __restrict__ packed_best)
{
  const int b = blockIdx.y;
  const int mbase = blockIdx.x * MG;
  const int tid = threadIdx.x;

  f4 g[MG]; float ga[MG];
#pragma unroll
  for (int j = 0; j < MG; j++) {
    g[j] = gt_boxes[b * MN + mbase + j];
    ga[j] = (g[j].z - g[j].x) * (g[j].w - g[j].y);
  }

  u64 best[MG];
#pragma unroll
  for (int j = 0; j < MG; j++) best[j] = 0ull;

  for (int p = tid; p < PN; p += 256) {
    f4 pr = priors[p];
    float px0 = pr.x - pr.z * 0.5f;
    float py0 = pr.y - pr.w * 0.5f;
    float px1 = pr.x + pr.z * 0.5f;
    float py1 = pr.y + pr.w * 0.5f;
    float pa  = (px1 - px0) * (py1 - py0);
    u32 key = 0xFFFFFFFFu - (u32)p;  // larger key = smaller p -> first-occurrence ties
#pragma unroll
    for (int j = 0; j < MG; j++) {
      float iw = fmaxf(fminf(px1, g[j].z) - fmaxf(px0, g[j].x), 0.0f);
      float ih = fmaxf(fminf(py1, g[j].w) - fmaxf(py0, g[j].y), 0.0f);
      float inter = iw * ih;
      float iou = inter / (pa + ga[j] - inter);
      u64 pk = ((u64)__float_as_uint(iou) << 32) | key;
      if (pk > best[j]) best[j] = pk;
    }
  }

  __shared__ u64 wred[4][MG];
  const int lane = tid & 63, wv = tid >> 6;
#pragma unroll
  for (int j = 0; j < MG; j++) {
    u64 v = best[j];
#pragma unroll
    for (int off = 1; off < 64; off <<= 1) {
      u64 o = shfl_xor_u64(v, off);
      if (o > v) v = o;
    }
    if (lane == 0) wred[wv][j] = v;
  }
  __syncthreads();
  if (tid < MG) {
    u64 v = wred[0][tid];
#pragma unroll
    for (int w = 1; w < 4; w++) { u64 o = wred[w][tid]; if (o > v) v = o; }
    packed_best[b * MN + mbase + tid] = v;
  }
}

// ---------------- K2: scatter override (sequential last-wins per batch) ----
__global__ void k_override(const u64* __restrict__ packed,
                           float* __restrict__ best_ovl,
                           int* __restrict__ best_idx)
{
  int b = threadIdx.x;
  if (b >= BN) return;
  for (int m = 0; m < MN; m++) {
    u64 pk = packed[b * MN + m];
    u32 pidx = 0xFFFFFFFFu - (u32)(pk & 0xFFFFFFFFull);
    best_idx[(size_t)b * PN + pidx] = m;
    best_ovl[(size_t)b * PN + pidx] = 1.0f;
  }
}

// ---------------- K3: fused loc loss + CE (the hot, memory-bound kernel) ----
__global__ __launch_bounds__(256)
void k_big(const f4* __restrict__ loc_preds,
           const float* __restrict__ conf_preds,
           const f4* __restrict__ priors,
           const f4* __restrict__ gt_boxes,
           const int* __restrict__ gt_labels,
           const float* __restrict__ best_ovl,
           const int* __restrict__ best_idx,
           float* __restrict__ ce_neg,
           int* __restrict__ pos_cnt,
           int* __restrict__ num_pos,
           double* __restrict__ acc)
{
  const int b = blockIdx.y;
  const int p = blockIdx.x * blockDim.x + threadIdx.x;
  float my_sl1 = 0.f, my_cep = 0.f; int my_pos = 0;
  if (p < PN) {
    const size_t rp = (size_t)b * PN + p;
    const float ovl = best_ovl[rp];
    const int gi = best_idx[rp];
    const bool pos = ovl > 0.5f;
    int cls = 0;
    if (pos) {
      cls = gt_labels[b * MN + gi];
      f4 g = gt_boxes[b * MN + gi];
      f4 pr = priors[p];
      float gx = (g.x + g.z) * 0.5f, gy = (g.y + g.w) * 0.5f;
      float gw = g.z - g.x, gh = g.w - g.y;
      f4 lp = loc_preds[rp];
      float d0 = lp.x - (gx - pr.x) / pr.z;
      float d1 = lp.y - (gy - pr.y) / pr.w;
      float d2 = lp.z - logf(gw / pr.z);
      float d3 = lp.w - logf(gh / pr.w);
      my_sl1 = sl1f(d0) + sl1f(d1) + sl1f(d2) + sl1f(d3);
      my_pos = 1;
    }
    const float* row = conf_preds + rp * (size_t)CN;
    float xt = row[cls];
    const f4* vrow = (const f4*)row;
    float mx = -3.0e38f, s = 0.f;
#pragma unroll
    for (int i = 0; i < 20; i++) {
      f4 v = vrow[i];
      float m4 = fmaxf(fmaxf(v.x, v.y), fmaxf(v.z, v.w));
      float nm = fmaxf(mx, m4);
      s = s * __expf(mx - nm) + __expf(v.x - nm) + __expf(v.y - nm)
            + __expf(v.z - nm) + __expf(v.w - nm);
      mx = nm;
    }
    {
      float x = row[80];
      float nm = fmaxf(mx, x);
      s = s * __expf(mx - nm) + __expf(x - nm);
      mx = nm;
    }
    float ce = mx + logf(s) - xt;
    ce = fmaxf(ce, 0.0f);   // keep bits sign-free for radix select
    if (pos) { my_cep = ce; ce_neg[rp] = 0.0f; }
    else     { ce_neg[rp] = ce; }
  }
  // block reduce (double) -> one atomic per block
  double dsl = (double)my_sl1, dce = (double)my_cep;
  int pc = my_pos;
#pragma unroll
  for (int off = 1; off < 64; off <<= 1) {
    dsl += __shfl_xor(dsl, off, 64);
    dce += __shfl_xor(dce, off, 64);
    pc  += __shfl_xor(pc, off, 64);
  }
  __shared__ double ssl[4], sce[4]; __shared__ int spc[4];
  const int lane = threadIdx.x & 63, wv = threadIdx.x >> 6;
  if (lane == 0) { ssl[wv] = dsl; sce[wv] = dce; spc[wv] = pc; }
  __syncthreads();
  if (threadIdx.x == 0) {
    double a = ssl[0] + ssl[1] + ssl[2] + ssl[3];
    double c = sce[0] + sce[1] + sce[2] + sce[3];
    int q = spc[0] + spc[1] + spc[2] + spc[3];
    if (a != 0.0) atomicAdd(&acc[0], a);
    if (c != 0.0) atomicAdd(&acc[1], c);
    if (q) { atomicAdd(num_pos, q); atomicAdd(&pos_cnt[b], q); }
  }
}

// ---------------- K4: per-batch exact top-k sum via radix select ------------
__global__ __launch_bounds__(1024)
void k_topk(const float* __restrict__ ce_neg,
            const int* __restrict__ pos_cnt,
            double* __restrict__ acc)
{
  const int b = blockIdx.x;
  const float* row = ce_neg + (size_t)b * PN;
  int k = pos_cnt[b] * 3;
  if (k < 1) k = 1;
  if (k > PN) k = PN;

  const int tid = threadIdx.x;
  const int wv = tid >> 6;
  __shared__ u32 hist[16][256];
  __shared__ u32 sh_prefix; __shared__ int sh_rem;

  u32 prefix = 0; int rem = k;
  for (int shift = 24; shift >= 0; shift -= 8) {
    for (int i = tid; i < 16 * 256; i += blockDim.x) ((u32*)hist)[i] = 0;
    __syncthreads();
    const u32 pmask = (shift == 24) ? 0u : (0xFFFFFFFFu << (shift + 8));
    for (int p = tid; p < PN; p += blockDim.x) {
      u32 u = __float_as_uint(row[p]);
      if ((u & pmask) == (prefix & pmask))
        atomicAdd(&hist[wv][(u >> shift) & 255], 1u);
    }
    __syncthreads();
    if (tid < 256) {
      u32 c = 0;
#pragma unroll
      for (int w = 0; w < 16; w++) c += hist[w][tid];
      hist[0][tid] = c;
    }
    __syncthreads();
    if (tid == 0) {
      u32 c = 0; int d = 255;
      for (; d >= 0; d--) { c += hist[0][d]; if ((int)c >= rem) break; }
      if (d < 0) d = 0;
      sh_prefix = prefix | ((u32)d << shift);
      sh_rem = rem - (int)(c - hist[0][d]);
    }
    __syncthreads();
    prefix = sh_prefix; rem = sh_rem;
    __syncthreads();
  }

  const float vstar = __uint_as_float(prefix);
  double sg = 0.0;
  for (int p = tid; p < PN; p += blockDim.x) {
    float v = row[p];
    if (__float_as_uint(v) > prefix) sg += (double)v;
  }
#pragma unroll
  for (int off = 1; off < 64; off <<= 1) sg += __shfl_xor(sg, off, 64);
  __shared__ double sred[16];
  if ((tid & 63) == 0) sred[wv] = sg;
  __syncthreads();
  if (tid == 0) {
    double t = 0;
    for (int w = 0; w < 16; w++) t += sred[w];
    t += (double)rem * (double)vstar;   // ties at v* contribute identically
    atomicAdd(&acc[2], t);
  }
}

// ---------------- K5: finalize ----------------
__global__ void k_final(const double* __restrict__ acc,
                        const int* __restrict__ num_pos,
                        float* __restrict__ out)
{
  int np = *num_pos; if (np < 1) np = 1;
  out[0] = (float)((acc[0] + acc[1] + acc[2]) / (double)np);
}

extern "C" void kernel_launch(void* const* d_in, const int* in_sizes, int n_in,
                              void* d_out, int out_size, void* d_ws, size_t ws_size,
                              hipStream_t stream)
{
  const f4*    loc    = (const f4*)d_in[0];
  const float* conf   = (const float*)d_in[1];
  const f4*    priors = (const f4*)d_in[2];
  const f4*    gt     = (const f4*)d_in[3];
  const int*   labels = (const int*)d_in[4];

  char* ws = (char*)d_ws;
  float* ce_neg   = (float*)(ws);
  float* best_ovl = (float*)(ws + OFF_OVL);
  int*   best_idx = (int*)(ws + OFF_IDX);
  u64*   packed   = (u64*)(ws + OFF_PACK);
  int*   pos_cnt  = (int*)(ws + OFF_PCNT);
  int*   num_pos  = (int*)(ws + OFF_NP);
  double* acc     = (double*)(ws + OFF_ACC);

  hipMemsetAsync(ws + ZERO_OFF, 0, ZERO_SZ, stream);

  k_prior_best<<<dim3((PN + 255) / 256, BN), 256, 0, stream>>>(priors, gt, best_ovl, best_idx);
  k_gt_best<<<dim3(MN / MG, BN), 256, 0, stream>>>(priors, gt, packed);
  k_override<<<1, 64, 0, stream>>>(packed, best_ovl, best_idx);
  k_big<<<dim3((PN + 255) / 256, BN), 256, 0, stream>>>(loc, conf, priors, gt, labels,
                                                        best_ovl, best_idx, ce_neg,
                                                        pos_cnt, num_pos, acc);
  k_topk<<<BN, 1024, 0, stream>>>(ce_neg, pos_cnt, acc);
  k_final<<<1, 1, 0, stream>>>(acc, num_pos, (float*)d_out);
}

// Round 3
// 432.426 us; speedup vs baseline: 1.5161x; 1.0010x over previous
//
#include <hip/hip_runtime.h>
#include <stdint.h>

#define PN 24564
#define BN 64
#define MN 32
#define CN 81
#define MG 4   // gt boxes per block in k_gt_best

typedef float f4 __attribute__((ext_vector_type(4)));
typedef unsigned long long u64;
typedef unsigned int u32;

// ---------------- workspace layout ----------------
constexpr size_t SZ_BP4   = (size_t)BN * PN * 4;        // 6,288,384
constexpr size_t OFF_OVL  = SZ_BP4;                     // best_ovl f32
constexpr size_t OFF_IDX  = 2 * SZ_BP4;                 // best_idx i32
constexpr size_t OFF_PACK = 3 * SZ_BP4;                 // packed u64 [BN*MN]
constexpr size_t SZ_PACK  = (size_t)BN * MN * 8;        // 16,384
constexpr size_t OFF_PCNT = OFF_PACK + SZ_PACK;         // per-batch pos count (BN i32)
constexpr size_t OFF_NP   = OFF_PCNT + BN * 4;          // global num_pos
constexpr size_t OFF_ACC  = OFF_NP + 8;                 // 3 doubles
constexpr size_t ZERO_OFF = OFF_PCNT;
constexpr size_t ZERO_WORDS = (BN * 4 + 8 + 24) / 4;    // 72 u32 words

__device__ __forceinline__ float sl1f(float d) {
  float ad = fabsf(d);
  return ad < 1.0f ? 0.5f * d * d : ad - 0.5f;
}

__device__ __forceinline__ u64 shfl_xor_u64(u64 v, int m) {
  u32 lo = (u32)v, hi = (u32)(v >> 32);
  lo = (u32)__shfl_xor((int)lo, m, 64);
  hi = (u32)__shfl_xor((int)hi, m, 64);
  return ((u64)hi << 32) | lo;
}

// ---------------- K0: zero the accumulator tail (replaces hipMemsetAsync) ---
__global__ void k_zero(u32* __restrict__ tail)
{
  if (threadIdx.x < ZERO_WORDS) tail[threadIdx.x] = 0u;
}

// ---------------- K1a: per-prior best gt (max/argmax over m) ----------------
__global__ __launch_bounds__(256)
void k_prior_best(const f4* __restrict__ priors,
                  const f4* __restrict__ gt_boxes,
                  float* __restrict__ best_ovl,
                  int* __restrict__ best_idx)
{
  const int b = blockIdx.y;
  const int tid = threadIdx.x;
  __shared__ f4 gt[MN];
  __shared__ float ga[MN];
  if (tid < MN) {
    f4 g = gt_boxes[b * MN + tid];
    gt[tid] = g;
    ga[tid] = (g.z - g.x) * (g.w - g.y);
  }
  __syncthreads();
  const int p = blockIdx.x * 256 + tid;
  if (p >= PN) return;
  f4 pr = priors[p];
  float px0 = pr.x - pr.z * 0.5f;
  float py0 = pr.y - pr.w * 0.5f;
  float px1 = pr.x + pr.z * 0.5f;
  float py1 = pr.y + pr.w * 0.5f;
  float pa  = (px1 - px0) * (py1 - py0);
  float bov = -1.0f; int bi = 0;
#pragma unroll
  for (int m = 0; m < MN; m++) {
    f4 g = gt[m];
    float iw = fmaxf(fminf(px1, g.z) - fmaxf(px0, g.x), 0.0f);
    float ih = fmaxf(fminf(py1, g.w) - fmaxf(py0, g.y), 0.0f);
    float inter = iw * ih;
    float iou = inter / (pa + ga[m] - inter);
    if (iou > bov) { bov = iou; bi = m; }
  }
  best_ovl[(size_t)b * PN + p] = bov;
  best_idx[(size_t)b * PN + p] = bi;
}

// ---------------- K1b: per-gt best prior (argmax over p), 4 gt per block ----
__global__ __launch_bounds__(256)
void k_gt_best(const f4* __restrict__ priors,
               const f4* __restrict__ gt_boxes,
               u64* __restrict__ packed_best)
{
  const int b = blockIdx.y;
  const int mbase = blockIdx.x * MG;
  const int tid = threadIdx.x;

  f4 g[MG]; float ga[MG];
#pragma unroll
  for (int j = 0; j < MG; j++) {
    g[j] = gt_boxes[b * MN + mbase + j];
    ga[j] = (g[j].z - g[j].x) * (g[j].w - g[j].y);
  }

  u64 best[MG];
#pragma unroll
  for (int j = 0; j < MG; j++) best[j] = 0ull;

  for (int p = tid; p < PN; p += 256) {
    f4 pr = priors[p];
    float px0 = pr.x - pr.z * 0.5f;
    float py0 = pr.y - pr.w * 0.5f;
    float px1 = pr.x + pr.z * 0.5f;
    float py1 = pr.y + pr.w * 0.5f;
    float pa  = (px1 - px0) * (py1 - py0);
    u32 key = 0xFFFFFFFFu - (u32)p;  // larger key = smaller p -> first-occurrence ties
#pragma unroll
    for (int j = 0; j < MG; j++) {
      float iw = fmaxf(fminf(px1, g[j].z) - fmaxf(px0, g[j].x), 0.0f);
      float ih = fmaxf(fminf(py1, g[j].w) - fmaxf(py0, g[j].y), 0.0f);
      float inter = iw * ih;
      float iou = inter / (pa + ga[j] - inter);
      u64 pk = ((u64)__float_as_uint(iou) << 32) | key;
      if (pk > best[j]) best[j] = pk;
    }
  }

  __shared__ u64 wred[4][MG];
  const int lane = tid & 63, wv = tid >> 6;
#pragma unroll
  for (int j = 0; j < MG; j++) {
    u64 v = best[j];
#pragma unroll
    for (int off = 1; off < 64; off <<= 1) {
      u64 o = shfl_xor_u64(v, off);
      if (o > v) v = o;
    }
    if (lane == 0) wred[wv][j] = v;
  }
  __syncthreads();
  if (tid < MG) {
    u64 v = wred[0][tid];
#pragma unroll
    for (int w = 1; w < 4; w++) { u64 o = wred[w][tid]; if (o > v) v = o; }
    packed_best[b * MN + mbase + tid] = v;
  }
}

// ---------------- K2: scatter override (sequential last-wins per batch) ----
__global__ void k_override(const u64* __restrict__ packed,
                           float* __restrict__ best_ovl,
                           int* __restrict__ best_idx)
{
  int b = threadIdx.x;
  if (b >= BN) return;
  for (int m = 0; m < MN; m++) {
    u64 pk = packed[b * MN + m];
    u32 pidx = 0xFFFFFFFFu - (u32)(pk & 0xFFFFFFFFull);
    best_idx[(size_t)b * PN + pidx] = m;
    best_ovl[(size_t)b * PN + pidx] = 1.0f;
  }
}

// ---------------- K3: fused loc loss + CE (the hot, memory-bound kernel) ----
__global__ __launch_bounds__(256)
void k_big(const f4* __restrict__ loc_preds,
           const float* __restrict__ conf_preds,
           const f4* __restrict__ priors,
           const f4* __restrict__ gt_boxes,
           const int* __restrict__ gt_labels,
           const float* __restrict__ best_ovl,
           const int* __restrict__ best_idx,
           float* __restrict__ ce_neg,
           int* __restrict__ pos_cnt,
           int* __restrict__ num_pos,
           double* __restrict__ acc)
{
  const int b = blockIdx.y;
  const int p = blockIdx.x * blockDim.x + threadIdx.x;
  float my_sl1 = 0.f, my_cep = 0.f; int my_pos = 0;
  if (p < PN) {
    const size_t rp = (size_t)b * PN + p;
    const float ovl = best_ovl[rp];
    const int gi = best_idx[rp];
    const bool pos = ovl > 0.5f;
    int cls = 0;
    if (pos) {
      cls = gt_labels[b * MN + gi];
      f4 g = gt_boxes[b * MN + gi];
      f4 pr = priors[p];
      float gx = (g.x + g.z) * 0.5f, gy = (g.y + g.w) * 0.5f;
      float gw = g.z - g.x, gh = g.w - g.y;
      f4 lp = loc_preds[rp];
      float d0 = lp.x - (gx - pr.x) / pr.z;
      float d1 = lp.y - (gy - pr.y) / pr.w;
      float d2 = lp.z - logf(gw / pr.z);
      float d3 = lp.w - logf(gh / pr.w);
      my_sl1 = sl1f(d0) + sl1f(d1) + sl1f(d2) + sl1f(d3);
      my_pos = 1;
    }
    const float* row = conf_preds + rp * (size_t)CN;
    float xt = row[cls];
    const f4* vrow = (const f4*)row;
    float mx = -3.0e38f, s = 0.f;
#pragma unroll
    for (int i = 0; i < 20; i++) {
      f4 v = vrow[i];
      float m4 = fmaxf(fmaxf(v.x, v.y), fmaxf(v.z, v.w));
      float nm = fmaxf(mx, m4);
      s = s * __expf(mx - nm) + __expf(v.x - nm) + __expf(v.y - nm)
            + __expf(v.z - nm) + __expf(v.w - nm);
      mx = nm;
    }
    {
      float x = row[80];
      float nm = fmaxf(mx, x);
      s = s * __expf(mx - nm) + __expf(x - nm);
      mx = nm;
    }
    float ce = mx + logf(s) - xt;
    ce = fmaxf(ce, 0.0f);   // keep bits sign-free for radix select
    if (pos) { my_cep = ce; ce_neg[rp] = 0.0f; }
    else     { ce_neg[rp] = ce; }
  }
  // block reduce (double) -> one atomic per block
  double dsl = (double)my_sl1, dce = (double)my_cep;
  int pc = my_pos;
#pragma unroll
  for (int off = 1; off < 64; off <<= 1) {
    dsl += __shfl_xor(dsl, off, 64);
    dce += __shfl_xor(dce, off, 64);
    pc  += __shfl_xor(pc, off, 64);
  }
  __shared__ double ssl[4], sce[4]; __shared__ int spc[4];
  const int lane = threadIdx.x & 63, wv = threadIdx.x >> 6;
  if (lane == 0) { ssl[wv] = dsl; sce[wv] = dce; spc[wv] = pc; }
  __syncthreads();
  if (threadIdx.x == 0) {
    double a = ssl[0] + ssl[1] + ssl[2] + ssl[3];
    double c = sce[0] + sce[1] + sce[2] + sce[3];
    int q = spc[0] + spc[1] + spc[2] + spc[3];
    if (a != 0.0) atomicAdd(&acc[0], a);
    if (c != 0.0) atomicAdd(&acc[1], c);
    if (q) { atomicAdd(num_pos, q); atomicAdd(&pos_cnt[b], q); }
  }
}

// ---------------- K4: per-batch exact top-k sum via radix select ------------
__global__ __launch_bounds__(1024)
void k_topk(const float* __restrict__ ce_neg,
            const int* __restrict__ pos_cnt,
            double* __restrict__ acc)
{
  const int b = blockIdx.x;
  const float* row = ce_neg + (size_t)b * PN;
  int k = pos_cnt[b] * 3;
  if (k < 1) k = 1;
  if (k > PN) k = PN;

  const int tid = threadIdx.x;
  const int wv = tid >> 6;
  __shared__ u32 hist[16][256];
  __shared__ u32 sh_prefix; __shared__ int sh_rem;

  u32 prefix = 0; int rem = k;
  for (int shift = 24; shift >= 0; shift -= 8) {
    for (int i = tid; i < 16 * 256; i += blockDim.x) ((u32*)hist)[i] = 0;
    __syncthreads();
    const u32 pmask = (shift == 24) ? 0u : (0xFFFFFFFFu << (shift + 8));
    for (int p = tid; p < PN; p += blockDim.x) {
      u32 u = __float_as_uint(row[p]);
      if ((u & pmask) == (prefix & pmask))
        atomicAdd(&hist[wv][(u >> shift) & 255], 1u);
    }
    __syncthreads();
    if (tid < 256) {
      u32 c = 0;
#pragma unroll
      for (int w = 0; w < 16; w++) c += hist[w][tid];
      hist[0][tid] = c;
    }
    __syncthreads();
    if (tid == 0) {
      u32 c = 0; int d = 255;
      for (; d >= 0; d--) { c += hist[0][d]; if ((int)c >= rem) break; }
      if (d < 0) d = 0;
      sh_prefix = prefix | ((u32)d << shift);
      sh_rem = rem - (int)(c - hist[0][d]);
    }
    __syncthreads();
    prefix = sh_prefix; rem = sh_rem;
    __syncthreads();
  }

  const float vstar = __uint_as_float(prefix);
  double sg = 0.0;
  for (int p = tid; p < PN; p += blockDim.x) {
    float v = row[p];
    if (__float_as_uint(v) > prefix) sg += (double)v;
  }
#pragma unroll
  for (int off = 1; off < 64; off <<= 1) sg += __shfl_xor(sg, off, 64);
  __shared__ double sred[16];
  if ((tid & 63) == 0) sred[wv] = sg;
  __syncthreads();
  if (tid == 0) {
    double t = 0;
    for (int w = 0; w < 16; w++) t += sred[w];
    t += (double)rem * (double)vstar;   // ties at v* contribute identically
    atomicAdd(&acc[2], t);
  }
}

// ---------------- K5: finalize ----------------
__global__ void k_final(const double* __restrict__ acc,
                        const int* __restrict__ num_pos,
                        float* __restrict__ out)
{
  int np = *num_pos; if (np < 1) np = 1;
  out[0] = (float)((acc[0] + acc[1] + acc[2]) / (double)np);
}

extern "C" void kernel_launch(void* const* d_in, const int* in_sizes, int n_in,
                              void* d_out, int out_size, void* d_ws, size_t ws_size,
                              hipStream_t stream)
{
  const f4*    loc    = (const f4*)d_in[0];
  const float* conf   = (const float*)d_in[1];
  const f4*    priors = (const f4*)d_in[2];
  const f4*    gt     = (const f4*)d_in[3];
  const int*   labels = (const int*)d_in[4];

  char* ws = (char*)d_ws;
  float* ce_neg   = (float*)(ws);
  float* best_ovl = (float*)(ws + OFF_OVL);
  int*   best_idx = (int*)(ws + OFF_IDX);
  u64*   packed   = (u64*)(ws + OFF_PACK);
  int*   pos_cnt  = (int*)(ws + OFF_PCNT);
  int*   num_pos  = (int*)(ws + OFF_NP);
  double* acc     = (double*)(ws + OFF_ACC);

  k_zero<<<1, 128, 0, stream>>>((u32*)(ws + ZERO_OFF));
  k_prior_best<<<dim3((PN + 255) / 256, BN), 256, 0, stream>>>(priors, gt, best_ovl, best_idx);
  k_gt_best<<<dim3(MN / MG, BN), 256, 0, stream>>>(priors, gt, packed);
  k_override<<<1, 64, 0, stream>>>(packed, best_ovl, best_idx);
  k_big<<<dim3((PN + 255) / 256, BN), 256, 0, stream>>>(loc, conf, priors, gt, labels,
                                                        best_ovl, best_idx, ce_neg,
                                                        pos_cnt, num_pos, acc);
  k_topk<<<BN, 1024, 0, stream>>>(ce_neg, pos_cnt, acc);
  k_final<<<1, 1, 0, stream>>>(acc, num_pos, (float*)d_out);
}